// Round 1
// baseline (1793.501 us; speedup 1.0000x reference)
//
#include <hip/hip_runtime.h>
#include <hip/hip_bf16.h>
#include <math.h>

#define S 2048
#define D 2048
#define NH 16
#define NKV 8
#define HD 128
#define TOPK 40
#define EPSR 1e-6f
#define SCALEF 0.08838834764831845f

// ---------------- fp32 GEMM: C[m][n] = alpha * sum_k A[m][k] * B[n][k] ----------------
// A: row-major M x K (lda), B: row-major N x K (ldb)  (i.e. C = A * B^T)
#define BM 64
#define BN 64
#define BK 32

__global__ __launch_bounds__(256) void gemm_rr(
    const float* __restrict__ A, int lda, size_t a_hs,
    const float* __restrict__ B, int ldb, size_t b_hs, int b_div,
    float* __restrict__ C, int ldc, size_t c_hs,
    int K, float alpha, int head0)
{
  int z = blockIdx.z;
  int h = head0 + z;
  A += (size_t)h * a_hs;
  B += (size_t)(h / b_div) * b_hs;
  C += (size_t)z * c_hs;

  __shared__ float As[BK][BM];
  __shared__ float Bs[BK][BN];
  int tid = threadIdx.x;
  int tx = tid & 15, ty = tid >> 4;
  int m0 = blockIdx.x * BM, n0 = blockIdx.y * BN;

  float acc[4][4] = {};
  for (int k0 = 0; k0 < K; k0 += BK) {
#pragma unroll
    for (int i = 0; i < 2; i++) {
      int f4 = tid + i * 256;      // 0..511
      int r  = f4 >> 3;            // 0..63
      int c  = (f4 & 7) * 4;       // 0..28
      float4 av = *(const float4*)&A[(size_t)(m0 + r) * lda + k0 + c];
      float4 bv = *(const float4*)&B[(size_t)(n0 + r) * ldb + k0 + c];
      As[c + 0][r] = av.x; As[c + 1][r] = av.y; As[c + 2][r] = av.z; As[c + 3][r] = av.w;
      Bs[c + 0][r] = bv.x; Bs[c + 1][r] = bv.y; Bs[c + 2][r] = bv.z; Bs[c + 3][r] = bv.w;
    }
    __syncthreads();
#pragma unroll
    for (int k = 0; k < BK; k++) {
      float4 a4 = *(const float4*)&As[k][ty * 4];
      float4 b4 = *(const float4*)&Bs[k][tx * 4];
      float av[4] = {a4.x, a4.y, a4.z, a4.w};
      float bv[4] = {b4.x, b4.y, b4.z, b4.w};
#pragma unroll
      for (int i2 = 0; i2 < 4; i2++)
#pragma unroll
        for (int j = 0; j < 4; j++)
          acc[i2][j] = fmaf(av[i2], bv[j], acc[i2][j]);
    }
    __syncthreads();
  }
#pragma unroll
  for (int i2 = 0; i2 < 4; i2++) {
    int m = m0 + ty * 4 + i2;
#pragma unroll
    for (int j = 0; j < 4; j++)
      C[(size_t)m * ldc + n0 + tx * 4 + j] = alpha * acc[i2][j];
  }
}

// ---------------- fused QKV GEMM with scatter to [head][s][d] buffers ----------------
__global__ __launch_bounds__(256) void gemm_qkv(
    const float* __restrict__ X,
    const float* __restrict__ Wq, const float* __restrict__ Wk, const float* __restrict__ Wv,
    float* __restrict__ qb, float* __restrict__ kb, float* __restrict__ vb)
{
  __shared__ float As[BK][BM];
  __shared__ float Bs[BK][BN];
  int tid = threadIdx.x;
  int tx = tid & 15, ty = tid >> 4;
  int m0 = blockIdx.x * BM, n0 = blockIdx.y * BN;

  const float* Bsrc;
  if (n0 < 2048)       Bsrc = Wq + (size_t)n0 * D;
  else if (n0 < 3072)  Bsrc = Wk + (size_t)(n0 - 2048) * D;
  else                 Bsrc = Wv + (size_t)(n0 - 3072) * D;

  float acc[4][4] = {};
  for (int k0 = 0; k0 < D; k0 += BK) {
#pragma unroll
    for (int i = 0; i < 2; i++) {
      int f4 = tid + i * 256;
      int r  = f4 >> 3;
      int c  = (f4 & 7) * 4;
      float4 av = *(const float4*)&X[(size_t)(m0 + r) * D + k0 + c];
      float4 bv = *(const float4*)&Bsrc[(size_t)r * D + k0 + c];
      As[c + 0][r] = av.x; As[c + 1][r] = av.y; As[c + 2][r] = av.z; As[c + 3][r] = av.w;
      Bs[c + 0][r] = bv.x; Bs[c + 1][r] = bv.y; Bs[c + 2][r] = bv.z; Bs[c + 3][r] = bv.w;
    }
    __syncthreads();
#pragma unroll
    for (int k = 0; k < BK; k++) {
      float4 a4 = *(const float4*)&As[k][ty * 4];
      float4 b4 = *(const float4*)&Bs[k][tx * 4];
      float av[4] = {a4.x, a4.y, a4.z, a4.w};
      float bv[4] = {b4.x, b4.y, b4.z, b4.w};
#pragma unroll
      for (int i2 = 0; i2 < 4; i2++)
#pragma unroll
        for (int j = 0; j < 4; j++)
          acc[i2][j] = fmaf(av[i2], bv[j], acc[i2][j]);
    }
    __syncthreads();
  }
#pragma unroll
  for (int i2 = 0; i2 < 4; i2++) {
    int m = m0 + ty * 4 + i2;
#pragma unroll
    for (int j = 0; j < 4; j++) {
      int n = n0 + tx * 4 + j;
      float val = acc[i2][j];
      if (n < 2048) {
        qb[(size_t)(n >> 7) * (S * HD) + (size_t)m * HD + (n & 127)] = val;
      } else if (n < 3072) {
        int nn = n - 2048;
        kb[(size_t)(nn >> 7) * (S * HD) + (size_t)m * HD + (nn & 127)] = val;
      } else {
        int nn = n - 3072;
        vb[(size_t)(nn >> 7) * (S * HD) + (size_t)m * HD + (nn & 127)] = val;
      }
    }
  }
}

// ---------------- per-(head,s) RMSNorm + RoPE, in place ----------------
__global__ __launch_bounds__(128) void rms_rope(
    float* __restrict__ qb, float* __restrict__ kb,
    const float* __restrict__ cosT, const float* __restrict__ sinT,
    const float* __restrict__ qw, const float* __restrict__ kw)
{
  int r = blockIdx.x;
  float* ptr; const float* w; int s;
  if (r < NH * S) { ptr = qb + (size_t)r * HD; w = qw; s = r & (S - 1); }
  else { int rr = r - NH * S; ptr = kb + (size_t)rr * HD; w = kw; s = rr & (S - 1); }

  int d = threadIdx.x;
  __shared__ float red[HD];
  __shared__ float nrm[HD];
  float v = ptr[d];
  red[d] = v * v;
  __syncthreads();
  for (int o = 64; o > 0; o >>= 1) {
    if (d < o) red[d] += red[d + o];
    __syncthreads();
  }
  float inv = rsqrtf(red[0] / (float)HD + EPSR);
  float nv = v * inv * w[d];
  nrm[d] = nv;
  __syncthreads();
  float other = nrm[d ^ 64];
  float rot = (d < 64) ? -other : other;
  float c  = cosT[(size_t)s * HD + d];
  float sn = sinT[(size_t)s * HD + d];
  ptr[d] = nv * c + rot * sn;
}

// ---------------- top-k threshold (radix select) + masked softmax + sparse PV ----------------
#define MAXK 256
#define CAND 1024

__device__ __forceinline__ float key_to_float(unsigned u) {
  unsigned f = (u & 0x80000000u) ? (u & 0x7FFFFFFFu) : ~u;
  return __uint_as_float(f);
}

__global__ __launch_bounds__(256) void topk_pv(
    const float* __restrict__ score, size_t score_hs,
    const float* __restrict__ vb, float* __restrict__ attn, int head0)
{
  int z = blockIdx.z;
  int h = head0 + z;
  int q = blockIdx.x;
  const float* srow = score + (size_t)z * score_hs + (size_t)q * S;
  const float* V = vb + (size_t)(h >> 1) * (S * HD);

  __shared__ unsigned key[S];
  __shared__ unsigned hist[256];
  __shared__ unsigned cand[CAND];
  __shared__ unsigned cand2[CAND];
  __shared__ float wL[MAXK];
  __shared__ unsigned short idxL[MAXK];
  __shared__ unsigned red[256];
  __shared__ float fred[256];
  __shared__ unsigned sh_bin, sh_rem, sh_cnt, sh_c2, sh_kc;

  int tid = threadIdx.x;

  // load + monotone map + row max
  unsigned lmax = 0;
  for (int j = tid; j < S; j += 256) {
    unsigned u = __float_as_uint(srow[j]);
    u = (u & 0x80000000u) ? ~u : (u | 0x80000000u);
    key[j] = u;
    lmax = max(lmax, u);
  }
  red[tid] = lmax;
  __syncthreads();
  for (int o = 128; o > 0; o >>= 1) {
    if (tid < o) red[tid] = max(red[tid], red[tid + o]);
    __syncthreads();
  }
  unsigned maxkey = red[0];
  float mf = key_to_float(maxkey);
  __syncthreads();

  // ---- radix round 0 over all 2048 keys (top byte) ----
  hist[tid] = 0;
  if (tid == 0) sh_cnt = 0;
  __syncthreads();
  for (int j = tid; j < S; j += 256) atomicAdd(&hist[key[j] >> 24], 1u);
  __syncthreads();
  // suffix sum
  for (int st = 1; st < 256; st <<= 1) {
    unsigned v2 = (tid + st < 256) ? hist[tid + st] : 0;
    __syncthreads();
    hist[tid] += v2;
    __syncthreads();
  }
  unsigned t = TOPK;
  {
    unsigned above = (tid < 255) ? hist[tid + 1] : 0;
    if (hist[tid] >= t && above < t) { sh_bin = tid; sh_rem = t - above; }
  }
  __syncthreads();
  unsigned bin = sh_bin; t = sh_rem;
  unsigned prefix = bin;

  // compact keys whose top byte == bin
  for (int j = tid; j < S; j += 256) {
    unsigned u = key[j];
    if ((u >> 24) == bin) {
      unsigned p = atomicAdd(&sh_cnt, 1u);
      if (p < CAND) cand[p] = u;
    }
  }
  __syncthreads();
  unsigned ccnt = min(sh_cnt, (unsigned)CAND);

  unsigned* src = cand;
  unsigned* dst = cand2;
  for (int shift = 16; shift >= 0; shift -= 8) {
    hist[tid] = 0;
    if (tid == 0) sh_c2 = 0;
    __syncthreads();
    for (int j = tid; j < (int)ccnt; j += 256) atomicAdd(&hist[(src[j] >> shift) & 255u], 1u);
    __syncthreads();
    for (int st = 1; st < 256; st <<= 1) {
      unsigned v2 = (tid + st < 256) ? hist[tid + st] : 0;
      __syncthreads();
      hist[tid] += v2;
      __syncthreads();
    }
    {
      unsigned above = (tid < 255) ? hist[tid + 1] : 0;
      if (hist[tid] >= t && above < t) { sh_bin = tid; sh_rem = t - above; }
    }
    __syncthreads();
    bin = sh_bin; t = sh_rem;
    prefix = (prefix << 8) | bin;
    if (shift > 0) {
      for (int j = tid; j < (int)ccnt; j += 256) {
        unsigned u = src[j];
        if (((u >> shift) & 255u) == bin) {
          unsigned p = atomicAdd(&sh_c2, 1u);
          if (p < CAND) dst[p] = u;
        }
      }
      __syncthreads();
      ccnt = min(sh_c2, (unsigned)CAND);
      unsigned* tmp = src; src = dst; dst = tmp;
    }
  }
  unsigned thr = prefix;  // bit pattern of 40th-largest score (monotone key space)

  // ---- gather kept entries (>= thr, plus diagonal), softmax weights ----
  if (tid == 0) sh_kc = 0;
  __syncthreads();
  for (int j = tid; j < S; j += 256) {
    unsigned u = key[j];
    if (u >= thr || j == q) {
      float sf = key_to_float(u);
      float wv = expf(sf - mf);
      unsigned p = atomicAdd(&sh_kc, 1u);
      if (p < MAXK) { wL[p] = wv; idxL[p] = (unsigned short)j; }
    }
  }
  __syncthreads();
  int cnt = (int)min(sh_kc, (unsigned)MAXK);

  float zl = 0.f;
  for (int p = tid; p < cnt; p += 256) zl += wL[p];
  fred[tid] = zl;
  __syncthreads();
  for (int o = 128; o > 0; o >>= 1) {
    if (tid < o) fred[tid] += fred[tid + o];
    __syncthreads();
  }
  float Zinv = 1.0f / fred[0];

  if (tid < HD) {
    float o = 0.f;
    for (int p = 0; p < cnt; p++)
      o = fmaf(wL[p], V[(size_t)idxL[p] * HD + tid], o);
    attn[(size_t)q * (NH * HD) + (size_t)h * HD + tid] = o * Zinv;
  }
}

// ---------------- launch ----------------
extern "C" void kernel_launch(void* const* d_in, const int* in_sizes, int n_in,
                              void* d_out, int out_size, void* d_ws, size_t ws_size,
                              hipStream_t stream) {
  const float* x    = (const float*)d_in[0];
  const float* cosT = (const float*)d_in[1];
  const float* sinT = (const float*)d_in[2];
  const float* Wq   = (const float*)d_in[3];
  const float* Wk   = (const float*)d_in[4];
  const float* Wv   = (const float*)d_in[5];
  const float* Wo   = (const float*)d_in[6];
  const float* qw   = (const float*)d_in[7];
  const float* kw   = (const float*)d_in[8];
  float* out = (float*)d_out;
  float* ws  = (float*)d_ws;

  float* qb    = ws;                 // 16*2048*128 = 4194304 floats
  float* kb    = ws + 4194304;       // 8*2048*128
  float* vb    = ws + 6291456;       // 8*2048*128
  float* attn  = ws + 8388608;       // 2048*2048
  float* score = ws + 12582912;      // 1 or 16 head slabs of 2048*2048

  size_t needAll = (12582912ull + (size_t)NH * S * S) * 4ull;  // ~319 MB
  bool allH = ws_size >= needAll;

  // 1. QKV projection (M=2048, N=4096, K=2048)
  gemm_qkv<<<dim3(32, 64, 1), 256, 0, stream>>>(x, Wq, Wk, Wv, qb, kb, vb);

  // 2. RMSNorm + RoPE on Q and K
  rms_rope<<<dim3((NH + NKV) * S, 1, 1), 128, 0, stream>>>(qb, kb, cosT, sinT, qw, kw);

  // 3+4. scores + topk/softmax/PV
  if (allH) {
    gemm_rr<<<dim3(32, 32, NH), 256, 0, stream>>>(
        qb, HD, (size_t)S * HD, kb, HD, (size_t)S * HD, 2,
        score, S, (size_t)S * S, HD, SCALEF, 0);
    topk_pv<<<dim3(S, 1, NH), 256, 0, stream>>>(score, (size_t)S * S, vb, attn, 0);
  } else {
    for (int h = 0; h < NH; h++) {
      gemm_rr<<<dim3(32, 32, 1), 256, 0, stream>>>(
          qb, HD, (size_t)S * HD, kb, HD, (size_t)S * HD, 2,
          score, S, 0, HD, SCALEF, h);
      topk_pv<<<dim3(S, 1, 1), 256, 0, stream>>>(score, 0, vb, attn, h);
    }
  }

  // 5. output projection (M=2048, N=2048, K=2048)
  gemm_rr<<<dim3(32, 32, 1), 256, 0, stream>>>(
      attn, D, 0, Wo, D, 0, 1, out, D, 0, D, 1.0f, 0);
}